// Round 4
// baseline (3462.865 us; speedup 1.0000x reference)
//
#include <hip/hip_runtime.h>

// LightGCN propagation: acc = (E + X1 + X2 + X3)/4, X_{k+1}[col] += w * X_k[row]
// N = 500000 nodes, DIM = 64, E = 1.25M edges, fp32 throughout.
// NOTE: harness passes integer inputs as int32 (reference int64 -> const int*).

#define NNODES   500000
#define DIMV     64
#define NEDGE    1250000
#define NELEM    (NNODES * DIMV)          // 32,000,000 floats
#define NELEM4   (NELEM / 4)              // 8,000,000 float4

// ---- init: acc = emb, A = emb, B = 0 -------------------------------------
__global__ __launch_bounds__(256) void lgcn_init(
    const float4* __restrict__ emb, float4* __restrict__ acc,
    float4* __restrict__ A, float4* __restrict__ B)
{
    int i = blockIdx.x * blockDim.x + threadIdx.x;
    int stride = gridDim.x * blockDim.x;
    for (; i < NELEM4; i += stride) {
        float4 v = emb[i];
        acc[i] = v;
        A[i]   = v;
        B[i]   = make_float4(0.f, 0.f, 0.f, 0.f);
    }
}

// ---- scatter: xnext[col] += w * xcur[row]   (atomic) ---------------------
// 16 threads per edge; each thread handles 4 consecutive dims via float4 load.
__global__ __launch_bounds__(256) void lgcn_scatter(
    const float* __restrict__ xcur, float* __restrict__ xnext,
    const int* __restrict__ row, const int* __restrict__ col,
    const float* __restrict__ w)
{
    int t = blockIdx.x * blockDim.x + threadIdx.x;
    int e = t >> 4;
    if (e >= NEDGE) return;
    int d = (t & 15) << 2;                 // dim offset 0,4,...,60

    int r = row[e];
    int c = col[e];
    // crash insurance only; indices are in-range by construction
    if ((unsigned)r >= NNODES || (unsigned)c >= NNODES) return;
    float wt = w[e];

    const float4 v = *reinterpret_cast<const float4*>(xcur + (size_t)r * DIMV + d);
    float* dst = xnext + (size_t)c * DIMV + d;
    atomicAdd(dst + 0, wt * v.x);
    atomicAdd(dst + 1, wt * v.y);
    atomicAdd(dst + 2, wt * v.z);
    atomicAdd(dst + 3, wt * v.w);
}

// ---- acc += X; Y = 0  (prepares Y as next layer's scatter target) --------
__global__ __launch_bounds__(256) void lgcn_addzero(
    float4* __restrict__ acc, const float4* __restrict__ X, float4* __restrict__ Y)
{
    int i = blockIdx.x * blockDim.x + threadIdx.x;
    int stride = gridDim.x * blockDim.x;
    for (; i < NELEM4; i += stride) {
        float4 a = acc[i];
        float4 x = X[i];
        a.x += x.x; a.y += x.y; a.z += x.z; a.w += x.w;
        acc[i] = a;
        Y[i] = make_float4(0.f, 0.f, 0.f, 0.f);
    }
}

// ---- final: acc = (acc + X) * 0.25 ---------------------------------------
__global__ __launch_bounds__(256) void lgcn_final(
    float4* __restrict__ acc, const float4* __restrict__ X)
{
    int i = blockIdx.x * blockDim.x + threadIdx.x;
    int stride = gridDim.x * blockDim.x;
    for (; i < NELEM4; i += stride) {
        float4 a = acc[i];
        float4 x = X[i];
        a.x = (a.x + x.x) * 0.25f;
        a.y = (a.y + x.y) * 0.25f;
        a.z = (a.z + x.z) * 0.25f;
        a.w = (a.w + x.w) * 0.25f;
        acc[i] = a;
    }
}

extern "C" void kernel_launch(void* const* d_in, const int* in_sizes, int n_in,
                              void* d_out, int out_size, void* d_ws, size_t ws_size,
                              hipStream_t stream) {
    const float* emb  = (const float*)d_in[0];                 // [N, 64] fp32
    const int*   eidx = (const int*)d_in[1];                   // [2, E] int32
    const float* ew   = (const float*)d_in[2];                 // [E] fp32
    float* acc = (float*)d_out;                                // [N, 64]

    const int* row = eidx;                                     // eidx[0, :]
    const int* col = eidx + NEDGE;                             // eidx[1, :]

    float* A = (float*)d_ws;                                   // 128 MB
    float* B = A + NELEM;                                      // 128 MB

    const int EW_BLOCKS = 2048;                                // grid-stride elementwise
    const int SC_BLOCKS = (NEDGE * 16 + 255) / 256;            // 16 thr/edge

    // acc = emb, A = emb, B = 0
    lgcn_init<<<EW_BLOCKS, 256, 0, stream>>>(
        (const float4*)emb, (float4*)acc, (float4*)A, (float4*)B);

    // layer 1: B += w * A[row]; acc += B; A = 0
    lgcn_scatter<<<SC_BLOCKS, 256, 0, stream>>>(A, B, row, col, ew);
    lgcn_addzero<<<EW_BLOCKS, 256, 0, stream>>>((float4*)acc, (const float4*)B, (float4*)A);

    // layer 2: A += w * B[row]; acc += A; B = 0
    lgcn_scatter<<<SC_BLOCKS, 256, 0, stream>>>(B, A, row, col, ew);
    lgcn_addzero<<<EW_BLOCKS, 256, 0, stream>>>((float4*)acc, (const float4*)A, (float4*)B);

    // layer 3: B += w * A[row]; acc = (acc + B) * 0.25
    lgcn_scatter<<<SC_BLOCKS, 256, 0, stream>>>(A, B, row, col, ew);
    lgcn_final<<<EW_BLOCKS, 256, 0, stream>>>((float4*)acc, (const float4*)B);
}

// Round 5
// 917.855 us; speedup vs baseline: 3.7728x; 3.7728x over previous
//
#include <hip/hip_runtime.h>

// LightGCN propagation via per-call CSR build + gather (no float atomics).
// out = (E + X1 + X2 + X3)/4,  X_{k+1}[c] = sum_{e: col[e]=c} w[e] * X_k[row[e]]
// N = 500000 nodes, DIM = 64, E = 1.25M edges, fp32.
// Harness passes integer inputs as int32.

#define NNODES   500000
#define DIMV     64
#define NEDGE    1250000
#define NELEM    (NNODES * DIMV)          // 32,000,000 floats
#define NELEM4   (NELEM / 4)

#define SCAN_BLK   256
#define SCAN_ITEMS 8
#define SCAN_CHUNK (SCAN_BLK * SCAN_ITEMS)              // 2048
#define NB1 ((NNODES + SCAN_CHUNK - 1) / SCAN_CHUNK)    // 245 (<= 256)

// ======================= CSR build =======================

__global__ __launch_bounds__(256) void lgcn_zero_cnt(int* __restrict__ cnt)
{
    int i = blockIdx.x * blockDim.x + threadIdx.x;
    int stride = gridDim.x * blockDim.x;
    for (; i < NNODES; i += stride) cnt[i] = 0;
}

__global__ __launch_bounds__(256) void lgcn_hist(
    const int* __restrict__ col, int* __restrict__ cnt)
{
    int e = blockIdx.x * blockDim.x + threadIdx.x;
    if (e >= NEDGE) return;
    int c = col[e];
    if ((unsigned)c >= NNODES) return;       // insurance; never triggers
    atomicAdd(&cnt[c], 1);
}

// pass 1: per-chunk exclusive scan of cnt -> startv, chunk totals -> bsum
__global__ __launch_bounds__(SCAN_BLK) void lgcn_scan1(
    const int* __restrict__ cnt, int* __restrict__ startv, int* __restrict__ bsum)
{
    __shared__ int sh[SCAN_BLK];
    int b = blockIdx.x;
    int base = b * SCAN_CHUNK;
    int tid = threadIdx.x;
    int v[SCAN_ITEMS];
    int local = 0;
    #pragma unroll
    for (int k = 0; k < SCAN_ITEMS; ++k) {
        int idx = base + tid * SCAN_ITEMS + k;
        v[k] = (idx < NNODES) ? cnt[idx] : 0;
        local += v[k];
    }
    sh[tid] = local;
    __syncthreads();
    for (int off = 1; off < SCAN_BLK; off <<= 1) {
        int x = (tid >= off) ? sh[tid - off] : 0;
        __syncthreads();
        sh[tid] += x;
        __syncthreads();
    }
    int run = (tid == 0) ? 0 : sh[tid - 1];
    if (tid == SCAN_BLK - 1) bsum[b] = sh[tid];
    #pragma unroll
    for (int k = 0; k < SCAN_ITEMS; ++k) {
        int idx = base + tid * SCAN_ITEMS + k;
        if (idx < NNODES) startv[idx] = run;
        run += v[k];
    }
}

// pass 2: exclusive scan of NB1 chunk totals (single block)
__global__ __launch_bounds__(SCAN_BLK) void lgcn_scan2(int* __restrict__ bsum)
{
    __shared__ int sh[SCAN_BLK];
    int tid = threadIdx.x;
    sh[tid] = (tid < NB1) ? bsum[tid] : 0;
    __syncthreads();
    for (int off = 1; off < SCAN_BLK; off <<= 1) {
        int x = (tid >= off) ? sh[tid - off] : 0;
        __syncthreads();
        sh[tid] += x;
        __syncthreads();
    }
    if (tid < NB1) bsum[tid] = (tid == 0) ? 0 : sh[tid - 1];
}

// pass 3: add chunk offsets; cursor = start; start[N] = E
__global__ __launch_bounds__(256) void lgcn_scan3(
    int* __restrict__ startv, int* __restrict__ cursor, const int* __restrict__ bsum)
{
    int i = blockIdx.x * blockDim.x + threadIdx.x;
    if (i < NNODES) {
        int s = startv[i] + bsum[i / SCAN_CHUNK];
        startv[i] = s;
        cursor[i] = s;
    }
    if (i == 0) startv[NNODES] = NEDGE;
}

__global__ __launch_bounds__(256) void lgcn_fill(
    const int* __restrict__ row, const int* __restrict__ col,
    const float* __restrict__ w, int* __restrict__ cursor, int2* __restrict__ pairs)
{
    int e = blockIdx.x * blockDim.x + threadIdx.x;
    if (e >= NEDGE) return;
    int c = col[e];
    if ((unsigned)c >= NNODES) return;       // must match lgcn_hist's guard
    int r = row[e];
    float wt = w[e];
    if ((unsigned)r >= NNODES) { r = 0; wt = 0.f; }   // insurance
    int p = atomicAdd(&cursor[c], 1);
    pairs[p] = make_int2(r, __float_as_int(wt));
}

// ======================= gather layers =======================
// MODE 0 (init):  xout = gather(src=emb); acc = emb + xout
// MODE 1 (mid):   xout = gather(src);     acc += xout
// MODE 2 (final): acc  = (acc + gather(src)) * 0.25
template<int MODE>
__global__ __launch_bounds__(256) void lgcn_gather(
    const float* __restrict__ src, float* __restrict__ xout,
    float* __restrict__ acc,
    const int2* __restrict__ pairs, const int* __restrict__ startv)
{
    int t = blockIdx.x * blockDim.x + threadIdx.x;
    int n = t >> 6;                 // one wave per node
    int lane = t & 63;              // one lane per dim
    if (n >= NNODES) return;
    int s = startv[n];
    int e = startv[n + 1];
    float sum = 0.f;
    for (int i = s; i < e; ++i) {
        int2 p = pairs[i];          // wave-uniform broadcast load
        sum += __int_as_float(p.y) * src[(size_t)p.x * DIMV + lane];
    }
    size_t o = (size_t)n * DIMV + lane;
    if (MODE == 0)      { xout[o] = sum; acc[o] = src[o] + sum; }
    else if (MODE == 1) { xout[o] = sum; acc[o] += sum; }
    else                { acc[o] = (acc[o] + sum) * 0.25f; }
}

// ======================= fallback: atomic scatter path =======================

__global__ __launch_bounds__(256) void lgcn_init(
    const float4* __restrict__ emb, float4* __restrict__ acc,
    float4* __restrict__ A, float4* __restrict__ B)
{
    int i = blockIdx.x * blockDim.x + threadIdx.x;
    int stride = gridDim.x * blockDim.x;
    for (; i < NELEM4; i += stride) {
        float4 v = emb[i];
        acc[i] = v;
        A[i]   = v;
        B[i]   = make_float4(0.f, 0.f, 0.f, 0.f);
    }
}

__global__ __launch_bounds__(256) void lgcn_scatter(
    const float* __restrict__ xcur, float* __restrict__ xnext,
    const int* __restrict__ row, const int* __restrict__ col,
    const float* __restrict__ w)
{
    int t = blockIdx.x * blockDim.x + threadIdx.x;
    int e = t >> 4;
    if (e >= NEDGE) return;
    int d = (t & 15) << 2;
    int r = row[e];
    int c = col[e];
    if ((unsigned)r >= NNODES || (unsigned)c >= NNODES) return;
    float wt = w[e];
    const float4 v = *reinterpret_cast<const float4*>(xcur + (size_t)r * DIMV + d);
    float* dst = xnext + (size_t)c * DIMV + d;
    atomicAdd(dst + 0, wt * v.x);
    atomicAdd(dst + 1, wt * v.y);
    atomicAdd(dst + 2, wt * v.z);
    atomicAdd(dst + 3, wt * v.w);
}

__global__ __launch_bounds__(256) void lgcn_addzero(
    float4* __restrict__ acc, const float4* __restrict__ X, float4* __restrict__ Y)
{
    int i = blockIdx.x * blockDim.x + threadIdx.x;
    int stride = gridDim.x * blockDim.x;
    for (; i < NELEM4; i += stride) {
        float4 a = acc[i];
        float4 x = X[i];
        a.x += x.x; a.y += x.y; a.z += x.z; a.w += x.w;
        acc[i] = a;
        Y[i] = make_float4(0.f, 0.f, 0.f, 0.f);
    }
}

__global__ __launch_bounds__(256) void lgcn_final(
    float4* __restrict__ acc, const float4* __restrict__ X)
{
    int i = blockIdx.x * blockDim.x + threadIdx.x;
    int stride = gridDim.x * blockDim.x;
    for (; i < NELEM4; i += stride) {
        float4 a = acc[i];
        float4 x = X[i];
        a.x = (a.x + x.x) * 0.25f;
        a.y = (a.y + x.y) * 0.25f;
        a.z = (a.z + x.z) * 0.25f;
        a.w = (a.w + x.w) * 0.25f;
        acc[i] = a;
    }
}

// ======================= launch =======================

extern "C" void kernel_launch(void* const* d_in, const int* in_sizes, int n_in,
                              void* d_out, int out_size, void* d_ws, size_t ws_size,
                              hipStream_t stream) {
    const float* emb  = (const float*)d_in[0];   // [N, 64] fp32
    const int*   eidx = (const int*)d_in[1];     // [2, E] int32
    const float* ew   = (const float*)d_in[2];   // [E] fp32
    float* acc = (float*)d_out;                  // [N, 64]

    const int* row = eidx;
    const int* col = eidx + NEDGE;

    // workspace layout for gather path
    float* X1     = (float*)d_ws;                        // 128e6 B
    float* X2     = X1 + NELEM;                          // 128e6 B
    int2*  pairs  = (int2*)(X2 + NELEM);                 // 10e6 B (8-aligned)
    int*   startv = (int*)(pairs + NEDGE);               // (N+1)*4
    int*   cursor = startv + (NNODES + 1);               // N*4
    int*   bsum   = cursor + NNODES;                     // NB1*4
    const size_t needed = (size_t)2 * NELEM * 4 + (size_t)NEDGE * 8
                        + ((size_t)NNODES + 1) * 4 + (size_t)NNODES * 4 + (size_t)NB1 * 4;

    const int EDGE_BLOCKS = (NEDGE + 255) / 256;
    const int NODE_BLOCKS = (NNODES + 255) / 256;
    const int WAVE_BLOCKS = ((NNODES * 64) + 255) / 256;   // wave per node

    if (ws_size >= needed) {
        // ---- CSR build (per call; deterministic work) ----
        lgcn_zero_cnt<<<1954, 256, 0, stream>>>(cursor);
        lgcn_hist<<<EDGE_BLOCKS, 256, 0, stream>>>(col, cursor);
        lgcn_scan1<<<NB1, SCAN_BLK, 0, stream>>>(cursor, startv, bsum);
        lgcn_scan2<<<1, SCAN_BLK, 0, stream>>>(bsum);
        lgcn_scan3<<<NODE_BLOCKS, 256, 0, stream>>>(startv, cursor, bsum);
        lgcn_fill<<<EDGE_BLOCKS, 256, 0, stream>>>(row, col, ew, cursor, pairs);

        // ---- 3 gather layers, acc fused into d_out ----
        lgcn_gather<0><<<WAVE_BLOCKS, 256, 0, stream>>>(emb, X1, acc, pairs, startv);
        lgcn_gather<1><<<WAVE_BLOCKS, 256, 0, stream>>>(X1, X2, acc, pairs, startv);
        lgcn_gather<2><<<WAVE_BLOCKS, 256, 0, stream>>>(X2, nullptr, acc, pairs, startv);
    } else {
        // ---- fallback: proven atomic-scatter path (round 4) ----
        float* A = (float*)d_ws;
        float* B = A + NELEM;
        const int SC_BLOCKS = (NEDGE * 16 + 255) / 256;
        lgcn_init<<<2048, 256, 0, stream>>>(
            (const float4*)emb, (float4*)acc, (float4*)A, (float4*)B);
        lgcn_scatter<<<SC_BLOCKS, 256, 0, stream>>>(A, B, row, col, ew);
        lgcn_addzero<<<2048, 256, 0, stream>>>((float4*)acc, (const float4*)B, (float4*)A);
        lgcn_scatter<<<SC_BLOCKS, 256, 0, stream>>>(B, A, row, col, ew);
        lgcn_addzero<<<2048, 256, 0, stream>>>((float4*)acc, (const float4*)A, (float4*)B);
        lgcn_scatter<<<SC_BLOCKS, 256, 0, stream>>>(A, B, row, col, ew);
        lgcn_final<<<2048, 256, 0, stream>>>((float4*)acc, (const float4*)B);
    }
}

// Round 6
// 763.847 us; speedup vs baseline: 4.5335x; 1.2016x over previous
//
#include <hip/hip_runtime.h>

// LightGCN propagation via per-call CSR build + MLP-optimized gather.
// out = (E + X1 + X2 + X3)/4,  X_{k+1}[c] = sum_{e: col[e]=c} w[e] * X_k[row[e]]
// N = 500000 nodes, DIM = 64, E = 1.25M edges, fp32. int inputs arrive as int32.

#define NNODES   500000
#define DIMV     64
#define NEDGE    1250000
#define NELEM    (NNODES * DIMV)          // 32,000,000 floats
#define NELEM4   (NELEM / 4)

#define SCAN_BLK   256
#define SCAN_ITEMS 8
#define SCAN_CHUNK (SCAN_BLK * SCAN_ITEMS)              // 2048
#define NB1 ((NNODES + SCAN_CHUNK - 1) / SCAN_CHUNK)    // 245 (<= 256)

// ======================= CSR build =======================

__global__ __launch_bounds__(256) void lgcn_zero_cnt(int* __restrict__ cnt)
{
    int i = blockIdx.x * blockDim.x + threadIdx.x;
    int stride = gridDim.x * blockDim.x;
    for (; i < NNODES; i += stride) cnt[i] = 0;
}

__global__ __launch_bounds__(256) void lgcn_hist(
    const int* __restrict__ col, int* __restrict__ cnt)
{
    int e = blockIdx.x * blockDim.x + threadIdx.x;
    if (e >= NEDGE) return;
    int c = col[e];
    if ((unsigned)c >= NNODES) return;       // insurance; never triggers
    atomicAdd(&cnt[c], 1);
}

__global__ __launch_bounds__(SCAN_BLK) void lgcn_scan1(
    const int* __restrict__ cnt, int* __restrict__ startv, int* __restrict__ bsum)
{
    __shared__ int sh[SCAN_BLK];
    int b = blockIdx.x;
    int base = b * SCAN_CHUNK;
    int tid = threadIdx.x;
    int v[SCAN_ITEMS];
    int local = 0;
    #pragma unroll
    for (int k = 0; k < SCAN_ITEMS; ++k) {
        int idx = base + tid * SCAN_ITEMS + k;
        v[k] = (idx < NNODES) ? cnt[idx] : 0;
        local += v[k];
    }
    sh[tid] = local;
    __syncthreads();
    for (int off = 1; off < SCAN_BLK; off <<= 1) {
        int x = (tid >= off) ? sh[tid - off] : 0;
        __syncthreads();
        sh[tid] += x;
        __syncthreads();
    }
    int run = (tid == 0) ? 0 : sh[tid - 1];
    if (tid == SCAN_BLK - 1) bsum[b] = sh[tid];
    #pragma unroll
    for (int k = 0; k < SCAN_ITEMS; ++k) {
        int idx = base + tid * SCAN_ITEMS + k;
        if (idx < NNODES) startv[idx] = run;
        run += v[k];
    }
}

__global__ __launch_bounds__(SCAN_BLK) void lgcn_scan2(int* __restrict__ bsum)
{
    __shared__ int sh[SCAN_BLK];
    int tid = threadIdx.x;
    sh[tid] = (tid < NB1) ? bsum[tid] : 0;
    __syncthreads();
    for (int off = 1; off < SCAN_BLK; off <<= 1) {
        int x = (tid >= off) ? sh[tid - off] : 0;
        __syncthreads();
        sh[tid] += x;
        __syncthreads();
    }
    if (tid < NB1) bsum[tid] = (tid == 0) ? 0 : sh[tid - 1];
}

__global__ __launch_bounds__(256) void lgcn_scan3(
    int* __restrict__ startv, int* __restrict__ cursor, const int* __restrict__ bsum)
{
    int i = blockIdx.x * blockDim.x + threadIdx.x;
    if (i < NNODES) {
        int s = startv[i] + bsum[i / SCAN_CHUNK];
        startv[i] = s;
        cursor[i] = s;
    }
    if (i == 0) startv[NNODES] = NEDGE;
}

__global__ __launch_bounds__(256) void lgcn_fill(
    const int* __restrict__ row, const int* __restrict__ col,
    const float* __restrict__ w, int* __restrict__ cursor, int2* __restrict__ pairs)
{
    int e = blockIdx.x * blockDim.x + threadIdx.x;
    if (e >= NEDGE) return;
    int c = col[e];
    if ((unsigned)c >= NNODES) return;       // must match lgcn_hist's guard
    int r = row[e];
    float wt = w[e];
    if ((unsigned)r >= NNODES) { r = 0; wt = 0.f; }   // insurance
    int p = atomicAdd(&cursor[c], 1);
    pairs[p] = make_int2(r, __float_as_int(wt));
}

// ======================= gather layers (MLP-optimized) =======================
// One wave per node, one lane per dim. Lanes cooperatively fetch up to 64
// (row, weight) pairs in a single parallel load; src gathers issued in
// predicated batches of 8 independent loads (batch predicate wave-uniform).
// MODE 0 (init):  aval = emb[o];  xout = sum; acc = aval + sum
// MODE 1 (mid):   aval = acc[o];  xout = sum; acc = aval + sum
// MODE 2 (final): aval = acc[o];  acc = (aval + sum) * 0.25
template<int MODE>
__global__ __launch_bounds__(256) void lgcn_gather(
    const float* __restrict__ src, float* __restrict__ xout,
    float* __restrict__ acc,
    const int2* __restrict__ pairs, const int* __restrict__ startv)
{
    int t = blockIdx.x * blockDim.x + threadIdx.x;
    int n = t >> 6;                 // one wave per node
    int lane = t & 63;              // one lane per dim
    if (n >= NNODES) return;

    size_t o = (size_t)n * DIMV + lane;
    // independent early load — overlaps the whole gather chain
    float aval = (MODE == 0) ? src[o] : acc[o];

    int s = startv[n];              // two adjacent loads, issued in parallel
    int e = startv[n + 1];
    int deg = e - s;

    // lane-parallel pairs fetch (covers first 64 edges)
    int2 mp = (lane < deg) ? pairs[s + lane] : make_int2(0, 0);

    float sum = 0.f;
    int dcap = (deg < 64) ? deg : 64;
    for (int j = 0; j < dcap; j += 8) {
        float v[8], wv[8];
        #pragma unroll
        for (int k = 0; k < 8; ++k) {
            int jj = j + k;
            if (jj < dcap) {        // wave-uniform predicate
                int   r = __shfl(mp.x, jj);
                wv[k]   = __int_as_float(__shfl(mp.y, jj));
                v[k]    = src[(size_t)r * DIMV + lane];   // 8 independent gathers
            } else { v[k] = 0.f; wv[k] = 0.f; }
        }
        #pragma unroll
        for (int k = 0; k < 8; ++k) sum = fmaf(wv[k], v[k], sum);
    }
    // rare tail: degree > 64
    for (int i = s + 64; i < e; ++i) {
        int2 p = pairs[i];
        sum = fmaf(__int_as_float(p.y), src[(size_t)p.x * DIMV + lane], sum);
    }

    if (MODE == 2) {
        acc[o] = (aval + sum) * 0.25f;
    } else {
        xout[o] = sum;
        acc[o]  = aval + sum;
    }
}

// ======================= fallback: atomic scatter path =======================

__global__ __launch_bounds__(256) void lgcn_init(
    const float4* __restrict__ emb, float4* __restrict__ acc,
    float4* __restrict__ A, float4* __restrict__ B)
{
    int i = blockIdx.x * blockDim.x + threadIdx.x;
    int stride = gridDim.x * blockDim.x;
    for (; i < NELEM4; i += stride) {
        float4 v = emb[i];
        acc[i] = v;
        A[i]   = v;
        B[i]   = make_float4(0.f, 0.f, 0.f, 0.f);
    }
}

__global__ __launch_bounds__(256) void lgcn_scatter(
    const float* __restrict__ xcur, float* __restrict__ xnext,
    const int* __restrict__ row, const int* __restrict__ col,
    const float* __restrict__ w)
{
    int t = blockIdx.x * blockDim.x + threadIdx.x;
    int e = t >> 4;
    if (e >= NEDGE) return;
    int d = (t & 15) << 2;
    int r = row[e];
    int c = col[e];
    if ((unsigned)r >= NNODES || (unsigned)c >= NNODES) return;
    float wt = w[e];
    const float4 v = *reinterpret_cast<const float4*>(xcur + (size_t)r * DIMV + d);
    float* dst = xnext + (size_t)c * DIMV + d;
    atomicAdd(dst + 0, wt * v.x);
    atomicAdd(dst + 1, wt * v.y);
    atomicAdd(dst + 2, wt * v.z);
    atomicAdd(dst + 3, wt * v.w);
}

__global__ __launch_bounds__(256) void lgcn_addzero(
    float4* __restrict__ acc, const float4* __restrict__ X, float4* __restrict__ Y)
{
    int i = blockIdx.x * blockDim.x + threadIdx.x;
    int stride = gridDim.x * blockDim.x;
    for (; i < NELEM4; i += stride) {
        float4 a = acc[i];
        float4 x = X[i];
        a.x += x.x; a.y += x.y; a.z += x.z; a.w += x.w;
        acc[i] = a;
        Y[i] = make_float4(0.f, 0.f, 0.f, 0.f);
    }
}

__global__ __launch_bounds__(256) void lgcn_final(
    float4* __restrict__ acc, const float4* __restrict__ X)
{
    int i = blockIdx.x * blockDim.x + threadIdx.x;
    int stride = gridDim.x * blockDim.x;
    for (; i < NELEM4; i += stride) {
        float4 a = acc[i];
        float4 x = X[i];
        a.x = (a.x + x.x) * 0.25f;
        a.y = (a.y + x.y) * 0.25f;
        a.z = (a.z + x.z) * 0.25f;
        a.w = (a.w + x.w) * 0.25f;
        acc[i] = a;
    }
}

// ======================= launch =======================

extern "C" void kernel_launch(void* const* d_in, const int* in_sizes, int n_in,
                              void* d_out, int out_size, void* d_ws, size_t ws_size,
                              hipStream_t stream) {
    const float* emb  = (const float*)d_in[0];   // [N, 64] fp32
    const int*   eidx = (const int*)d_in[1];     // [2, E] int32
    const float* ew   = (const float*)d_in[2];   // [E] fp32
    float* acc = (float*)d_out;                  // [N, 64]

    const int* row = eidx;
    const int* col = eidx + NEDGE;

    // workspace layout (identical footprint to round 5)
    float* X1     = (float*)d_ws;                        // 128e6 B
    float* X2     = X1 + NELEM;                          // 128e6 B
    int2*  pairs  = (int2*)(X2 + NELEM);                 // 10e6 B (8-aligned)
    int*   startv = (int*)(pairs + NEDGE);               // (N+1)*4
    int*   cursor = startv + (NNODES + 1);               // N*4
    int*   bsum   = cursor + NNODES;                     // NB1*4
    const size_t needed = (size_t)2 * NELEM * 4 + (size_t)NEDGE * 8
                        + ((size_t)NNODES + 1) * 4 + (size_t)NNODES * 4 + (size_t)NB1 * 4;

    const int EDGE_BLOCKS = (NEDGE + 255) / 256;
    const int NODE_BLOCKS = (NNODES + 255) / 256;
    const int WAVE_BLOCKS = ((NNODES * 64) + 255) / 256;   // wave per node

    if (ws_size >= needed) {
        // ---- CSR build ----
        lgcn_zero_cnt<<<1954, 256, 0, stream>>>(cursor);
        lgcn_hist<<<EDGE_BLOCKS, 256, 0, stream>>>(col, cursor);
        lgcn_scan1<<<NB1, SCAN_BLK, 0, stream>>>(cursor, startv, bsum);
        lgcn_scan2<<<1, SCAN_BLK, 0, stream>>>(bsum);
        lgcn_scan3<<<NODE_BLOCKS, 256, 0, stream>>>(startv, cursor, bsum);
        lgcn_fill<<<EDGE_BLOCKS, 256, 0, stream>>>(row, col, ew, cursor, pairs);

        // ---- 3 gather layers, acc fused into d_out ----
        lgcn_gather<0><<<WAVE_BLOCKS, 256, 0, stream>>>(emb, X1, acc, pairs, startv);
        lgcn_gather<1><<<WAVE_BLOCKS, 256, 0, stream>>>(X1, X2, acc, pairs, startv);
        lgcn_gather<2><<<WAVE_BLOCKS, 256, 0, stream>>>(X2, nullptr, acc, pairs, startv);
    } else {
        // ---- fallback: proven atomic-scatter path ----
        float* A = (float*)d_ws;
        float* B = A + NELEM;
        const int SC_BLOCKS = (NEDGE * 16 + 255) / 256;
        lgcn_init<<<2048, 256, 0, stream>>>(
            (const float4*)emb, (float4*)acc, (float4*)A, (float4*)B);
        lgcn_scatter<<<SC_BLOCKS, 256, 0, stream>>>(A, B, row, col, ew);
        lgcn_addzero<<<2048, 256, 0, stream>>>((float4*)acc, (const float4*)B, (float4*)A);
        lgcn_scatter<<<SC_BLOCKS, 256, 0, stream>>>(B, A, row, col, ew);
        lgcn_addzero<<<2048, 256, 0, stream>>>((float4*)acc, (const float4*)A, (float4*)B);
        lgcn_scatter<<<SC_BLOCKS, 256, 0, stream>>>(A, B, row, col, ew);
        lgcn_final<<<2048, 256, 0, stream>>>((float4*)acc, (const float4*)B);
    }
}

// Round 7
// 626.966 us; speedup vs baseline: 5.5232x; 1.2183x over previous
//
#include <hip/hip_runtime.h>

// LightGCN propagation via per-call CSR build + 8-nodes-per-wave gather.
// out = (E + X1 + X2 + X3)/4,  X_{k+1}[c] = sum_{e: col[e]=c} w[e] * X_k[row[e]]
// N = 500000 nodes, DIM = 64, E = 1.25M edges, fp32. int inputs arrive as int32.

#define NNODES   500000
#define DIMV     64
#define NEDGE    1250000
#define NELEM    (NNODES * DIMV)          // 32,000,000 floats
#define NELEM4   (NELEM / 4)
#define GRP      8                        // nodes per wave (N divisible by 8)

#define SCAN_BLK   256
#define SCAN_ITEMS 8
#define SCAN_CHUNK (SCAN_BLK * SCAN_ITEMS)              // 2048
#define NB1 ((NNODES + SCAN_CHUNK - 1) / SCAN_CHUNK)    // 245 (<= 256)

// ======================= CSR build =======================

__global__ __launch_bounds__(256) void lgcn_zero_cnt(int* __restrict__ cnt)
{
    int i = blockIdx.x * blockDim.x + threadIdx.x;
    int stride = gridDim.x * blockDim.x;
    for (; i < NNODES; i += stride) cnt[i] = 0;
}

__global__ __launch_bounds__(256) void lgcn_hist(
    const int* __restrict__ col, int* __restrict__ cnt)
{
    int e = blockIdx.x * blockDim.x + threadIdx.x;
    if (e >= NEDGE) return;
    int c = col[e];
    if ((unsigned)c >= NNODES) return;       // insurance; never triggers
    atomicAdd(&cnt[c], 1);
}

__global__ __launch_bounds__(SCAN_BLK) void lgcn_scan1(
    const int* __restrict__ cnt, int* __restrict__ startv, int* __restrict__ bsum)
{
    __shared__ int sh[SCAN_BLK];
    int b = blockIdx.x;
    int base = b * SCAN_CHUNK;
    int tid = threadIdx.x;
    int v[SCAN_ITEMS];
    int local = 0;
    #pragma unroll
    for (int k = 0; k < SCAN_ITEMS; ++k) {
        int idx = base + tid * SCAN_ITEMS + k;
        v[k] = (idx < NNODES) ? cnt[idx] : 0;
        local += v[k];
    }
    sh[tid] = local;
    __syncthreads();
    for (int off = 1; off < SCAN_BLK; off <<= 1) {
        int x = (tid >= off) ? sh[tid - off] : 0;
        __syncthreads();
        sh[tid] += x;
        __syncthreads();
    }
    int run = (tid == 0) ? 0 : sh[tid - 1];
    if (tid == SCAN_BLK - 1) bsum[b] = sh[tid];
    #pragma unroll
    for (int k = 0; k < SCAN_ITEMS; ++k) {
        int idx = base + tid * SCAN_ITEMS + k;
        if (idx < NNODES) startv[idx] = run;
        run += v[k];
    }
}

__global__ __launch_bounds__(SCAN_BLK) void lgcn_scan2(int* __restrict__ bsum)
{
    __shared__ int sh[SCAN_BLK];
    int tid = threadIdx.x;
    sh[tid] = (tid < NB1) ? bsum[tid] : 0;
    __syncthreads();
    for (int off = 1; off < SCAN_BLK; off <<= 1) {
        int x = (tid >= off) ? sh[tid - off] : 0;
        __syncthreads();
        sh[tid] += x;
        __syncthreads();
    }
    if (tid < NB1) bsum[tid] = (tid == 0) ? 0 : sh[tid - 1];
}

__global__ __launch_bounds__(256) void lgcn_scan3(
    int* __restrict__ startv, int* __restrict__ cursor, const int* __restrict__ bsum)
{
    int i = blockIdx.x * blockDim.x + threadIdx.x;
    if (i < NNODES) {
        int s = startv[i] + bsum[i / SCAN_CHUNK];
        startv[i] = s;
        cursor[i] = s;
    }
    if (i == 0) startv[NNODES] = NEDGE;
}

__global__ __launch_bounds__(256) void lgcn_fill(
    const int* __restrict__ row, const int* __restrict__ col,
    const float* __restrict__ w, int* __restrict__ cursor, int2* __restrict__ pairs)
{
    int e = blockIdx.x * blockDim.x + threadIdx.x;
    if (e >= NEDGE) return;
    int c = col[e];
    if ((unsigned)c >= NNODES) return;       // must match lgcn_hist's guard
    int r = row[e];
    float wt = w[e];
    if ((unsigned)r >= NNODES) { r = 0; wt = 0.f; }   // insurance
    int p = atomicAdd(&cursor[c], 1);
    pairs[p] = make_int2(r, __float_as_int(wt));
}

// ======================= gather layers: 8 nodes / wave =======================
// Consecutive nodes have contiguous CSR ranges -> one lane-parallel pairs load
// covers the whole group. Edge -> node routing via wave-uniform branch chain
// on group-relative edge index (boundaries b1..b7).
// MODE 0 (init):  aval = src[o];  xout = sum; acc = aval + sum
// MODE 1 (mid):   aval = acc[o];  xout = sum; acc = aval + sum
// MODE 2 (final): aval = acc[o];  acc = (aval + sum) * 0.25
template<int MODE>
__global__ __launch_bounds__(256) void lgcn_gather8(
    const float* __restrict__ src, float* __restrict__ xout,
    float* __restrict__ acc,
    const int2* __restrict__ pairs, const int* __restrict__ startv)
{
    int t = blockIdx.x * blockDim.x + threadIdx.x;
    int wid = t >> 6;               // one wave per GRP nodes
    int lane = t & 63;              // one lane per dim
    int n0 = wid * GRP;
    if (n0 >= NNODES) return;

    // lane-parallel startv fetch: startv[n0 .. n0+GRP]  (GRP+1 = 9 values)
    int sv = (lane <= GRP) ? startv[n0 + lane] : 0;
    const int s0   = __shfl(sv, 0);
    const int b1   = __shfl(sv, 1) - s0;
    const int b2   = __shfl(sv, 2) - s0;
    const int b3   = __shfl(sv, 3) - s0;
    const int b4   = __shfl(sv, 4) - s0;
    const int b5   = __shfl(sv, 5) - s0;
    const int b6   = __shfl(sv, 6) - s0;
    const int b7   = __shfl(sv, 7) - s0;
    const int tote = __shfl(sv, 8) - s0;   // total edges in group

    const size_t o0 = (size_t)n0 * DIMV + lane;

    // independent early loads — overlap the whole gather chain
    float a0, a1, a2, a3, a4, a5, a6, a7;
    if (MODE == 0) {
        a0 = src[o0];       a1 = src[o0 + 64];  a2 = src[o0 + 128]; a3 = src[o0 + 192];
        a4 = src[o0 + 256]; a5 = src[o0 + 320]; a6 = src[o0 + 384]; a7 = src[o0 + 448];
    } else {
        a0 = acc[o0];       a1 = acc[o0 + 64];  a2 = acc[o0 + 128]; a3 = acc[o0 + 192];
        a4 = acc[o0 + 256]; a5 = acc[o0 + 320]; a6 = acc[o0 + 384]; a7 = acc[o0 + 448];
    }

    float m0 = 0.f, m1 = 0.f, m2 = 0.f, m3 = 0.f,
          m4 = 0.f, m5 = 0.f, m6 = 0.f, m7 = 0.f;

    for (int base = 0; base < tote; base += 64) {
        int chunk = tote - base; if (chunk > 64) chunk = 64;
        int2 mp = (lane < chunk) ? pairs[s0 + base + lane] : make_int2(0, 0);
        for (int j = 0; j < chunk; j += 8) {
            float v[8], wv[8];
            #pragma unroll
            for (int k = 0; k < 8; ++k) {
                int jj = j + k;
                if (jj < chunk) {          // wave-uniform predicate
                    int r = __shfl(mp.x, jj);
                    wv[k] = __int_as_float(__shfl(mp.y, jj));
                    v[k]  = src[(size_t)r * DIMV + lane];   // independent gathers
                } else { v[k] = 0.f; wv[k] = 0.f; }
            }
            #pragma unroll
            for (int k = 0; k < 8; ++k) {
                int jj = base + j + k;     // group-relative edge index (uniform)
                // padding lanes contribute 0 regardless of routing
                if      (jj < b1) m0 = fmaf(wv[k], v[k], m0);
                else if (jj < b2) m1 = fmaf(wv[k], v[k], m1);
                else if (jj < b3) m2 = fmaf(wv[k], v[k], m2);
                else if (jj < b4) m3 = fmaf(wv[k], v[k], m3);
                else if (jj < b5) m4 = fmaf(wv[k], v[k], m4);
                else if (jj < b6) m5 = fmaf(wv[k], v[k], m5);
                else if (jj < b7) m6 = fmaf(wv[k], v[k], m6);
                else              m7 = fmaf(wv[k], v[k], m7);
            }
        }
    }

    if (MODE == 2) {
        acc[o0]       = (a0 + m0) * 0.25f;
        acc[o0 + 64]  = (a1 + m1) * 0.25f;
        acc[o0 + 128] = (a2 + m2) * 0.25f;
        acc[o0 + 192] = (a3 + m3) * 0.25f;
        acc[o0 + 256] = (a4 + m4) * 0.25f;
        acc[o0 + 320] = (a5 + m5) * 0.25f;
        acc[o0 + 384] = (a6 + m6) * 0.25f;
        acc[o0 + 448] = (a7 + m7) * 0.25f;
    } else {
        xout[o0]       = m0;  acc[o0]       = a0 + m0;
        xout[o0 + 64]  = m1;  acc[o0 + 64]  = a1 + m1;
        xout[o0 + 128] = m2;  acc[o0 + 128] = a2 + m2;
        xout[o0 + 192] = m3;  acc[o0 + 192] = a3 + m3;
        xout[o0 + 256] = m4;  acc[o0 + 256] = a4 + m4;
        xout[o0 + 320] = m5;  acc[o0 + 320] = a5 + m5;
        xout[o0 + 384] = m6;  acc[o0 + 384] = a6 + m6;
        xout[o0 + 448] = m7;  acc[o0 + 448] = a7 + m7;
    }
}

// ======================= fallback: atomic scatter path =======================

__global__ __launch_bounds__(256) void lgcn_init(
    const float4* __restrict__ emb, float4* __restrict__ acc,
    float4* __restrict__ A, float4* __restrict__ B)
{
    int i = blockIdx.x * blockDim.x + threadIdx.x;
    int stride = gridDim.x * blockDim.x;
    for (; i < NELEM4; i += stride) {
        float4 v = emb[i];
        acc[i] = v;
        A[i]   = v;
        B[i]   = make_float4(0.f, 0.f, 0.f, 0.f);
    }
}

__global__ __launch_bounds__(256) void lgcn_scatter(
    const float* __restrict__ xcur, float* __restrict__ xnext,
    const int* __restrict__ row, const int* __restrict__ col,
    const float* __restrict__ w)
{
    int t = blockIdx.x * blockDim.x + threadIdx.x;
    int e = t >> 4;
    if (e >= NEDGE) return;
    int d = (t & 15) << 2;
    int r = row[e];
    int c = col[e];
    if ((unsigned)r >= NNODES || (unsigned)c >= NNODES) return;
    float wt = w[e];
    const float4 v = *reinterpret_cast<const float4*>(xcur + (size_t)r * DIMV + d);
    float* dst = xnext + (size_t)c * DIMV + d;
    atomicAdd(dst + 0, wt * v.x);
    atomicAdd(dst + 1, wt * v.y);
    atomicAdd(dst + 2, wt * v.z);
    atomicAdd(dst + 3, wt * v.w);
}

__global__ __launch_bounds__(256) void lgcn_addzero(
    float4* __restrict__ acc, const float4* __restrict__ X, float4* __restrict__ Y)
{
    int i = blockIdx.x * blockDim.x + threadIdx.x;
    int stride = gridDim.x * blockDim.x;
    for (; i < NELEM4; i += stride) {
        float4 a = acc[i];
        float4 x = X[i];
        a.x += x.x; a.y += x.y; a.z += x.z; a.w += x.w;
        acc[i] = a;
        Y[i] = make_float4(0.f, 0.f, 0.f, 0.f);
    }
}

__global__ __launch_bounds__(256) void lgcn_final(
    float4* __restrict__ acc, const float4* __restrict__ X)
{
    int i = blockIdx.x * blockDim.x + threadIdx.x;
    int stride = gridDim.x * blockDim.x;
    for (; i < NELEM4; i += stride) {
        float4 a = acc[i];
        float4 x = X[i];
        a.x = (a.x + x.x) * 0.25f;
        a.y = (a.y + x.y) * 0.25f;
        a.z = (a.z + x.z) * 0.25f;
        a.w = (a.w + x.w) * 0.25f;
        acc[i] = a;
    }
}

// ======================= launch =======================

extern "C" void kernel_launch(void* const* d_in, const int* in_sizes, int n_in,
                              void* d_out, int out_size, void* d_ws, size_t ws_size,
                              hipStream_t stream) {
    const float* emb  = (const float*)d_in[0];   // [N, 64] fp32
    const int*   eidx = (const int*)d_in[1];     // [2, E] int32
    const float* ew   = (const float*)d_in[2];   // [E] fp32
    float* acc = (float*)d_out;                  // [N, 64]

    const int* row = eidx;
    const int* col = eidx + NEDGE;

    // workspace layout (identical footprint to round 5/6)
    float* X1     = (float*)d_ws;                        // 128e6 B
    float* X2     = X1 + NELEM;                          // 128e6 B
    int2*  pairs  = (int2*)(X2 + NELEM);                 // 10e6 B (8-aligned)
    int*   startv = (int*)(pairs + NEDGE);               // (N+1)*4
    int*   cursor = startv + (NNODES + 1);               // N*4
    int*   bsum   = cursor + NNODES;                     // NB1*4
    const size_t needed = (size_t)2 * NELEM * 4 + (size_t)NEDGE * 8
                        + ((size_t)NNODES + 1) * 4 + (size_t)NNODES * 4 + (size_t)NB1 * 4;

    const int EDGE_BLOCKS = (NEDGE + 255) / 256;
    const int NODE_BLOCKS = (NNODES + 255) / 256;
    const int G8_BLOCKS   = ((NNODES / GRP) * 64 + 255) / 256;   // 62500 waves

    if (ws_size >= needed) {
        // ---- CSR build ----
        lgcn_zero_cnt<<<1954, 256, 0, stream>>>(cursor);
        lgcn_hist<<<EDGE_BLOCKS, 256, 0, stream>>>(col, cursor);
        lgcn_scan1<<<NB1, SCAN_BLK, 0, stream>>>(cursor, startv, bsum);
        lgcn_scan2<<<1, SCAN_BLK, 0, stream>>>(bsum);
        lgcn_scan3<<<NODE_BLOCKS, 256, 0, stream>>>(startv, cursor, bsum);
        lgcn_fill<<<EDGE_BLOCKS, 256, 0, stream>>>(row, col, ew, cursor, pairs);

        // ---- 3 gather layers, acc fused into d_out ----
        lgcn_gather8<0><<<G8_BLOCKS, 256, 0, stream>>>(emb, X1, acc, pairs, startv);
        lgcn_gather8<1><<<G8_BLOCKS, 256, 0, stream>>>(X1, X2, acc, pairs, startv);
        lgcn_gather8<2><<<G8_BLOCKS, 256, 0, stream>>>(X2, nullptr, acc, pairs, startv);
    } else {
        // ---- fallback: proven atomic-scatter path ----
        float* A = (float*)d_ws;
        float* B = A + NELEM;
        const int SC_BLOCKS = (NEDGE * 16 + 255) / 256;
        lgcn_init<<<2048, 256, 0, stream>>>(
            (const float4*)emb, (float4*)acc, (float4*)A, (float4*)B);
        lgcn_scatter<<<SC_BLOCKS, 256, 0, stream>>>(A, B, row, col, ew);
        lgcn_addzero<<<2048, 256, 0, stream>>>((float4*)acc, (const float4*)B, (float4*)A);
        lgcn_scatter<<<SC_BLOCKS, 256, 0, stream>>>(B, A, row, col, ew);
        lgcn_addzero<<<2048, 256, 0, stream>>>((float4*)acc, (const float4*)A, (float4*)B);
        lgcn_scatter<<<SC_BLOCKS, 256, 0, stream>>>(A, B, row, col, ew);
        lgcn_final<<<2048, 256, 0, stream>>>((float4*)acc, (const float4*)B);
    }
}